// Round 8
// baseline (511.483 us; speedup 1.0000x reference)
//
#include <hip/hip_runtime.h>
#include <stdint.h>

#define TT 512
#define BB 4096
#define NT4 1024   // tiles of 4 batch columns
#define LOG2E 1.4426950408889634f

typedef _Float16 half8_t __attribute__((ext_vector_type(8)));
typedef float f32x4 __attribute__((ext_vector_type(4)));

union FragU { uint4 u4; half8_t h8; };

__device__ __forceinline__ float rcp_(float x){ return __builtin_amdgcn_rcpf(x); }
__device__ __forceinline__ float exp2_(float x){ return __builtin_amdgcn_exp2f(x); }
__device__ __forceinline__ float elu_(float x){ return x > 0.0f ? x : (exp2_(x * LOG2E) - 1.0f); }
__device__ __forceinline__ int mini_(int a, int b){ return a < b ? a : b; }
__device__ __forceinline__ float maskhi_(float x){ return __uint_as_float(__float_as_uint(x) & 0xFFFFE000u); }

__device__ __forceinline__ f32x4 MFMA(half8_t a, half8_t b, f32x4 c) {
    return __builtin_amdgcn_mfma_f32_16x16x32_f16(a, b, c, 0, 0, 0);
}

__device__ __forceinline__ f32x4 ld4_(const float* p){ return *(const f32x4*)p; }

// pack 8 f32 -> 8 f16 with scale (A-fragment slice; row = lane&15, k = 8*(lane>>4)+e)
__device__ __forceinline__ half8_t packA8s(const float* s, float sc) {
    half8_t h;
#pragma unroll
    for (int k = 0; k < 8; ++k) h[k] = (_Float16)(s[k] * sc);
    return h;
}

// select reg j (runtime 0..3) from f32x4 via 3 cndmask (static indices only)
__device__ __forceinline__ float sel4_(f32x4 a, int j) {
    float lo = (j & 1) ? a[1] : a[0];
    float hi = (j & 1) ? a[3] : a[2];
    return (j & 2) ? hi : lo;
}

// One-unit LSTM cell. Inputs PRESCALED: i,f,o by log2e; g by 2*log2e.
// Shared-rcp trick: all four gate sigmoids use ONE v_rcp via the product
// R = rcp((1+ei)(1+ef)(1+eg)(1+eo)); 1/(1+ek) = R * prod_{j!=k}(1+ej).
// 7 transcendentals total (5 exp2 + 2 rcp) vs naive 10.
__device__ __forceinline__ float cell1_(float gi, float gf, float gg, float go, float& c) {
    float ei = exp2_(-gi), ef = exp2_(-gf), eg = exp2_(-gg), eo = exp2_(-go);
    float ai = 1.0f + ei, af = 1.0f + ef, ag = 1.0f + eg, ao = 1.0f + eo;
    float p2 = ai * af, p3 = p2 * ag, P = p3 * ao;
    float R  = rcp_(P);
    float sgo = ag * ao;
    float I = R * (af * sgo);
    float F = R * (ai * sgo);
    float G = fmaf(2.0f, R * (p2 * ao), -1.0f);
    float O = R * p3;
    c = fmaf(F, c, I * G);
    float et = exp2_(c * (-2.0f * LOG2E));
    float T  = fmaf(2.0f, rcp_(1.0f + et), -1.0f);
    return O * T;
}

// Dup-4 scheme: 4 real cols per chain; B cols 0-15 all read col c=b&3, so the
// 4 C-regs of lane (q,b) are all valid for col c; lane uses reg j=b>>2 =>
// unit u = 4q+j. 1 unit/lane. Each WAVE runs BOTH directions' chains
// interleaved (independent recurrences) so their latencies hide each other.
//
// Per-chain LDS region (320 B): col c at c*80: bytes [0..31] hi fp16 units
// 0..15, [32..63] lo residual. Lane writes b16 hi at c*80+u*2, lo at +32.
// B-frag read: b128 at c*80+q*16 = [hi u0-7|hi u8-15|lo u0-7|lo u8-15]
// (HW-verified K=32=[h_hi;h_lo] layout: col=lane&15 (dup), k=8q+e).

// ---------------- phase A: layer 0 (input dim 1), both directions fused ----------------
struct PA {
    const float *x;
    const float *WihF, *WhhF, *bihF, *bhhF;
    const float *WihB, *WhhB, *bihB, *bhhB;
    char* ws;   // [tile4][t][256B]: col c at c*64: [f u0-15 hi | b u0-15 hi] fp16
};

__global__ __launch_bounds__(256) void phaseA_k(PA p) {
    __shared__ uint4 lds4[4 * 40];   // 4 waves x (2 chains x 320 B)
    const int tid = threadIdx.x;
    const int lane = tid & 63;
    const int wv   = tid >> 6;
    char* ldsF = (char*)lds4 + wv * 640;
    char* ldsB = ldsF + 320;
    const int q = lane >> 4, b = lane & 15, c = b & 3, j = b >> 2;
    const int tile = blockIdx.x * 4 + wv;   // 1024 tiles, each wave does f+b

    const float SC0 = LOG2E, SC1 = LOG2E, SC2 = 2.0f*LOG2E, SC3 = LOG2E;

    // ---- chain F weights ----
    half8_t fwhh0 = packA8s(p.WhhF + (     b)*16 + 8*(q&1), SC0);
    half8_t fwhh1 = packA8s(p.WhhF + (16 + b)*16 + 8*(q&1), SC1);
    half8_t fwhh2 = packA8s(p.WhhF + (32 + b)*16 + 8*(q&1), SC2);
    half8_t fwhh3 = packA8s(p.WhhF + (48 + b)*16 + 8*(q&1), SC3);
    f32x4 fbias0 = (ld4_(p.bihF +      4*q) + ld4_(p.bhhF +      4*q)) * SC0;
    f32x4 fbias1 = (ld4_(p.bihF + 16 + 4*q) + ld4_(p.bhhF + 16 + 4*q)) * SC1;
    f32x4 fbias2 = (ld4_(p.bihF + 32 + 4*q) + ld4_(p.bhhF + 32 + 4*q)) * SC2;
    f32x4 fbias3 = (ld4_(p.bihF + 48 + 4*q) + ld4_(p.bhhF + 48 + 4*q)) * SC3;
    f32x4 fwih0 = ld4_(p.WihF +      4*q) * SC0;
    f32x4 fwih1 = ld4_(p.WihF + 16 + 4*q) * SC1;
    f32x4 fwih2 = ld4_(p.WihF + 32 + 4*q) * SC2;
    f32x4 fwih3 = ld4_(p.WihF + 48 + 4*q) * SC3;

    // ---- chain B weights ----
    half8_t bwhh0 = packA8s(p.WhhB + (     b)*16 + 8*(q&1), SC0);
    half8_t bwhh1 = packA8s(p.WhhB + (16 + b)*16 + 8*(q&1), SC1);
    half8_t bwhh2 = packA8s(p.WhhB + (32 + b)*16 + 8*(q&1), SC2);
    half8_t bwhh3 = packA8s(p.WhhB + (48 + b)*16 + 8*(q&1), SC3);
    f32x4 bbias0 = (ld4_(p.bihB +      4*q) + ld4_(p.bhhB +      4*q)) * SC0;
    f32x4 bbias1 = (ld4_(p.bihB + 16 + 4*q) + ld4_(p.bhhB + 16 + 4*q)) * SC1;
    f32x4 bbias2 = (ld4_(p.bihB + 32 + 4*q) + ld4_(p.bhhB + 32 + 4*q)) * SC2;
    f32x4 bbias3 = (ld4_(p.bihB + 48 + 4*q) + ld4_(p.bhhB + 48 + 4*q)) * SC3;
    f32x4 bwih0 = ld4_(p.WihB +      4*q) * SC0;
    f32x4 bwih1 = ld4_(p.WihB + 16 + 4*q) * SC1;
    f32x4 bwih2 = ld4_(p.WihB + 32 + 4*q) * SC2;
    f32x4 bwih3 = ld4_(p.WihB + 48 + 4*q) * SC3;

    const int u   = 4*q + j;
    const int rdo = c*80 + q*16;       // frag read offset
    const int who = c*80 + u*2;        // hi b16 write (lo at +32)

    { unsigned int* z = (unsigned int*)ldsF;     // zero both chain regions
      for (int k = lane; k < 160; k += 64) z[k] = 0u; }
    __builtin_amdgcn_wave_barrier();

    float cF = 0.f, cB = 0.f;

    const char* xbase = (const char*)p.x + ((size_t)tile*4 + c)*TT*4;  // per-lane col row
    char*       wsbase = p.ws + (size_t)tile*TT*256;
    const int   wF = c*64 + u*2;        // fwd hi half slot
    const int   wB = c*64 + 32 + u*2;   // bwd hi half slot

    auto xldF = [&](int s)->float { return *(const float*)(xbase + (size_t)mini_(s, TT-1)*4); };
    auto xldB = [&](int s)->float { return *(const float*)(xbase + (size_t)(TT-1-mini_(s, TT-1))*4); };

    auto stepF = [&](float xv, int t) {
        FragU hf; hf.u4 = *(const uint4*)(ldsF + rdo);
        f32x4 a0 = fbias0 + fwih0 * xv;
        f32x4 a1 = fbias1 + fwih1 * xv;
        f32x4 a2 = fbias2 + fwih2 * xv;
        f32x4 a3 = fbias3 + fwih3 * xv;
        a0 = MFMA(fwhh0, hf.h8, a0);
        a1 = MFMA(fwhh1, hf.h8, a1);
        a2 = MFMA(fwhh2, hf.h8, a2);
        a3 = MFMA(fwhh3, hf.h8, a3);
        float h = cell1_(sel4_(a0, j), sel4_(a1, j), sel4_(a2, j), sel4_(a3, j), cF);
        float m = maskhi_(h);
        __fp16 hi16 = (__fp16)m;
        __fp16 lo16 = (__fp16)(h - m);
        *(__fp16*)(ldsF + who) = hi16;
        *(__fp16*)(ldsF + who + 32) = lo16;
        *(__fp16*)(wsbase + (size_t)t*256 + wF) = hi16;
    };
    auto stepB = [&](float xv, int t) {
        FragU hf; hf.u4 = *(const uint4*)(ldsB + rdo);
        f32x4 a0 = bbias0 + bwih0 * xv;
        f32x4 a1 = bbias1 + bwih1 * xv;
        f32x4 a2 = bbias2 + bwih2 * xv;
        f32x4 a3 = bbias3 + bwih3 * xv;
        a0 = MFMA(bwhh0, hf.h8, a0);
        a1 = MFMA(bwhh1, hf.h8, a1);
        a2 = MFMA(bwhh2, hf.h8, a2);
        a3 = MFMA(bwhh3, hf.h8, a3);
        float h = cell1_(sel4_(a0, j), sel4_(a1, j), sel4_(a2, j), sel4_(a3, j), cB);
        float m = maskhi_(h);
        __fp16 hi16 = (__fp16)m;
        __fp16 lo16 = (__fp16)(h - m);
        *(__fp16*)(ldsB + who) = hi16;
        *(__fp16*)(ldsB + who + 32) = lo16;
        *(__fp16*)(wsbase + (size_t)t*256 + wB) = hi16;
    };

    float xF = xldF(0), xB = xldB(0);
    for (int s = 0; s < TT; ++s) {
        float xFn = xldF(s+1);
        float xBn = xldB(s+1);
        stepF(xF, s);
        stepB(xB, TT-1-s);
        xF = xFn; xB = xBn;
    }
}

// ---------------- phase B: layer 1 (input dim 32 from ws), both directions fused ----------------
struct PB {
    const float *WihF, *WhhF, *bihF, *bhhF;
    const float *WihB, *WhhB, *bihB, *bhhB;
    const char* ws;
    float* hT;   // [dir][batch][16] f32
};

__global__ __launch_bounds__(256) void phaseB_k(PB p) {
    __shared__ uint4 lds4[4 * 40];
    const int tid = threadIdx.x;
    const int lane = tid & 63;
    const int wv   = tid >> 6;
    char* ldsF = (char*)lds4 + wv * 640;
    char* ldsB = ldsF + 320;
    const int q = lane >> 4, b = lane & 15, c = b & 3, j = b >> 2;
    const int tile = blockIdx.x * 4 + wv;

    const float SC0 = LOG2E, SC1 = LOG2E, SC2 = 2.0f*LOG2E, SC3 = LOG2E;

    half8_t fwih0 = packA8s(p.WihF + (     b)*32 + 8*q, SC0);  // K=32 = [h0f;h0b]
    half8_t fwih1 = packA8s(p.WihF + (16 + b)*32 + 8*q, SC1);
    half8_t fwih2 = packA8s(p.WihF + (32 + b)*32 + 8*q, SC2);
    half8_t fwih3 = packA8s(p.WihF + (48 + b)*32 + 8*q, SC3);
    half8_t fwhh0 = packA8s(p.WhhF + (     b)*16 + 8*(q&1), SC0);
    half8_t fwhh1 = packA8s(p.WhhF + (16 + b)*16 + 8*(q&1), SC1);
    half8_t fwhh2 = packA8s(p.WhhF + (32 + b)*16 + 8*(q&1), SC2);
    half8_t fwhh3 = packA8s(p.WhhF + (48 + b)*16 + 8*(q&1), SC3);
    f32x4 fbias0 = (ld4_(p.bihF +      4*q) + ld4_(p.bhhF +      4*q)) * SC0;
    f32x4 fbias1 = (ld4_(p.bihF + 16 + 4*q) + ld4_(p.bhhF + 16 + 4*q)) * SC1;
    f32x4 fbias2 = (ld4_(p.bihF + 32 + 4*q) + ld4_(p.bhhF + 32 + 4*q)) * SC2;
    f32x4 fbias3 = (ld4_(p.bihF + 48 + 4*q) + ld4_(p.bhhF + 48 + 4*q)) * SC3;

    half8_t bwih0 = packA8s(p.WihB + (     b)*32 + 8*q, SC0);
    half8_t bwih1 = packA8s(p.WihB + (16 + b)*32 + 8*q, SC1);
    half8_t bwih2 = packA8s(p.WihB + (32 + b)*32 + 8*q, SC2);
    half8_t bwih3 = packA8s(p.WihB + (48 + b)*32 + 8*q, SC3);
    half8_t bwhh0 = packA8s(p.WhhB + (     b)*16 + 8*(q&1), SC0);
    half8_t bwhh1 = packA8s(p.WhhB + (16 + b)*16 + 8*(q&1), SC1);
    half8_t bwhh2 = packA8s(p.WhhB + (32 + b)*16 + 8*(q&1), SC2);
    half8_t bwhh3 = packA8s(p.WhhB + (48 + b)*16 + 8*(q&1), SC3);
    f32x4 bbias0 = (ld4_(p.bihB +      4*q) + ld4_(p.bhhB +      4*q)) * SC0;
    f32x4 bbias1 = (ld4_(p.bihB + 16 + 4*q) + ld4_(p.bhhB + 16 + 4*q)) * SC1;
    f32x4 bbias2 = (ld4_(p.bihB + 32 + 4*q) + ld4_(p.bhhB + 32 + 4*q)) * SC2;
    f32x4 bbias3 = (ld4_(p.bihB + 48 + 4*q) + ld4_(p.bhhB + 48 + 4*q)) * SC3;

    const int u   = 4*q + j;
    const int rdo = c*80 + q*16;
    const int who = c*80 + u*2;

    { unsigned int* z = (unsigned int*)ldsF;
      for (int k = lane; k < 160; k += 64) z[k] = 0u; }
    __builtin_amdgcn_wave_barrier();

    float cF = 0.f, cB = 0.f;
    float hF = 0.f, hB = 0.f;

    const char* wsbase = p.ws + (size_t)tile*TT*256;
    const int   xoff   = c*64 + q*16;

    auto xldF = [&](int s)->uint4 {
        return *(const uint4*)(wsbase + (size_t)mini_(s, TT-1)*256 + xoff);
    };
    auto xldB = [&](int s)->uint4 {
        return *(const uint4*)(wsbase + (size_t)(TT-1-mini_(s, TT-1))*256 + xoff);
    };

    auto stepF = [&](uint4 xin) {
        FragU xf; xf.u4 = xin;
        FragU hf; hf.u4 = *(const uint4*)(ldsF + rdo);
        f32x4 a0 = MFMA(fwih0, xf.h8, fbias0);
        f32x4 a1 = MFMA(fwih1, xf.h8, fbias1);
        f32x4 a2 = MFMA(fwih2, xf.h8, fbias2);
        f32x4 a3 = MFMA(fwih3, xf.h8, fbias3);
        a0 = MFMA(fwhh0, hf.h8, a0);
        a1 = MFMA(fwhh1, hf.h8, a1);
        a2 = MFMA(fwhh2, hf.h8, a2);
        a3 = MFMA(fwhh3, hf.h8, a3);
        hF = cell1_(sel4_(a0, j), sel4_(a1, j), sel4_(a2, j), sel4_(a3, j), cF);
        float m = maskhi_(hF);
        *(__fp16*)(ldsF + who) = (__fp16)m;
        *(__fp16*)(ldsF + who + 32) = (__fp16)(hF - m);
    };
    auto stepB = [&](uint4 xin) {
        FragU xf; xf.u4 = xin;
        FragU hf; hf.u4 = *(const uint4*)(ldsB + rdo);
        f32x4 a0 = MFMA(bwih0, xf.h8, bbias0);
        f32x4 a1 = MFMA(bwih1, xf.h8, bbias1);
        f32x4 a2 = MFMA(bwih2, xf.h8, bbias2);
        f32x4 a3 = MFMA(bwih3, xf.h8, bbias3);
        a0 = MFMA(bwhh0, hf.h8, a0);
        a1 = MFMA(bwhh1, hf.h8, a1);
        a2 = MFMA(bwhh2, hf.h8, a2);
        a3 = MFMA(bwhh3, hf.h8, a3);
        hB = cell1_(sel4_(a0, j), sel4_(a1, j), sel4_(a2, j), sel4_(a3, j), cB);
        float m = maskhi_(hB);
        *(__fp16*)(ldsB + who) = (__fp16)m;
        *(__fp16*)(ldsB + who + 32) = (__fp16)(hB - m);
    };

    uint4 xF = xldF(0), xB = xldB(0);
    for (int s = 0; s < TT; ++s) {
        uint4 xFn = xldF(s+1);
        uint4 xBn = xldB(s+1);
        stepF(xF);
        stepB(xB);
        xF = xFn; xB = xBn;
    }

    const int batch = tile*4 + c;
    p.hT[((size_t)batch)*16 + u] = hF;
    p.hT[((size_t)BB + batch)*16 + u] = hB;
}

// ---------------- phase C: MLP head ----------------
struct PC {
    const float* hT;
    const float *W1, *b1, *W2, *b2;
    float* out;
};

__global__ __launch_bounds__(64) void head_k(PC p) {
    const int B = blockIdx.x * 64 + threadIdx.x;
    const float* hf = p.hT + (size_t)B*16;
    const float* hb = p.hT + ((size_t)BB + B)*16;

    float z0[32];
#pragma unroll
    for (int k = 0; k < 16; ++k) z0[k] = elu_(hb[k]);       // feat = [hT_b, hT_f]
#pragma unroll
    for (int k = 0; k < 16; ++k) z0[16+k] = elu_(hf[k]);

    float z1[25];
#pragma unroll
    for (int o = 0; o < 25; ++o) {
        float a = p.b1[o];
#pragma unroll
        for (int k = 0; k < 32; ++k) a = fmaf(p.W1[o*32 + k], z0[k], a);
        z1[o] = elu_(a);
    }
#pragma unroll
    for (int o = 0; o < 20; ++o) {
        float a = p.b2[o];
#pragma unroll
        for (int k = 0; k < 25; ++k) a = fmaf(p.W2[o*25 + k], z1[k], a);
        p.out[(size_t)B*20 + o] = elu_(a);
    }
}

extern "C" void kernel_launch(void* const* d_in, const int* in_sizes, int n_in,
                              void* d_out, int out_size, void* d_ws, size_t ws_size,
                              hipStream_t stream) {
    (void)in_sizes; (void)n_in; (void)out_size;

    const size_t frag_bytes = (size_t)NT4 * TT * 256;                 // 128 MiB
    const size_t hT_bytes   = (size_t)2 * BB * 16 * sizeof(float);    // 512 KiB
    size_t hT_off = (ws_size >= frag_bytes + hT_bytes) ? frag_bytes
                                                       : (ws_size - hT_bytes);
    char* ws = (char*)d_ws;
    float* hT = (float*)(ws + hT_off);

    PA pa;
    pa.x = (const float*)d_in[0];
    pa.WihF = (const float*)d_in[1];  pa.WhhF = (const float*)d_in[2];
    pa.bihF = (const float*)d_in[3];  pa.bhhF = (const float*)d_in[4];
    pa.WihB = (const float*)d_in[5];  pa.WhhB = (const float*)d_in[6];
    pa.bihB = (const float*)d_in[7];  pa.bhhB = (const float*)d_in[8];
    pa.ws = ws;
    hipLaunchKernelGGL(phaseA_k, dim3(256), dim3(256), 0, stream, pa);

    PB pb;
    pb.WihF = (const float*)d_in[9];   pb.WhhF = (const float*)d_in[10];
    pb.bihF = (const float*)d_in[11];  pb.bhhF = (const float*)d_in[12];
    pb.WihB = (const float*)d_in[13];  pb.WhhB = (const float*)d_in[14];
    pb.bihB = (const float*)d_in[15];  pb.bhhB = (const float*)d_in[16];
    pb.ws = ws; pb.hT = hT;
    hipLaunchKernelGGL(phaseB_k, dim3(256), dim3(256), 0, stream, pb);

    PC pc;
    pc.hT = hT;
    pc.W1 = (const float*)d_in[17]; pc.b1 = (const float*)d_in[18];
    pc.W2 = (const float*)d_in[19]; pc.b2 = (const float*)d_in[20];
    pc.out = (float*)d_out;
    hipLaunchKernelGGL(head_k, dim3(BB/64), dim3(64), 0, stream, pc);
}

// Round 9
// 291.835 us; speedup vs baseline: 1.7526x; 1.7526x over previous
//
#include <hip/hip_runtime.h>
#include <stdint.h>

#define TT 512
#define BB 4096
#define NT8 512   // tiles of 8 batch columns
#define LOG2E 1.4426950408889634f

typedef _Float16 half8_t __attribute__((ext_vector_type(8)));
typedef __fp16 fp16x2_t __attribute__((ext_vector_type(2)));
typedef float f32x4 __attribute__((ext_vector_type(4)));
typedef float f32x2 __attribute__((ext_vector_type(2)));

union FragU { uint4 u4; half8_t h8; };
union PkU { fp16x2_t h2; unsigned int u; };

__device__ __forceinline__ float rcp_(float x){ return __builtin_amdgcn_rcpf(x); }
__device__ __forceinline__ float exp2_(float x){ return __builtin_amdgcn_exp2f(x); }
__device__ __forceinline__ float elu_(float x){ return x > 0.0f ? x : (exp2_(x * LOG2E) - 1.0f); }
__device__ __forceinline__ int mini_(int a, int b){ return a < b ? a : b; }
__device__ __forceinline__ float maskhi_(float x){ return __uint_as_float(__float_as_uint(x) & 0xFFFFE000u); }
__device__ __forceinline__ unsigned int pkrtz_(float a, float b){
    PkU p; p.h2 = __builtin_amdgcn_cvt_pkrtz(a, b); return p.u;
}

__device__ __forceinline__ f32x4 MFMA(half8_t a, half8_t b, f32x4 c) {
    return __builtin_amdgcn_mfma_f32_16x16x32_f16(a, b, c, 0, 0, 0);
}

__device__ __forceinline__ f32x4 ld4_(const float* p){ return *(const f32x4*)p; }

// pack 8 f32 -> 8 f16 with scale (A-fragment slice; row = lane&15, k = 8*(lane>>4)+e)
__device__ __forceinline__ half8_t packA8s(const float* s, float sc) {
    half8_t h;
#pragma unroll
    for (int k = 0; k < 8; ++k) h[k] = (_Float16)(s[k] * sc);
    return h;
}

// Two-unit LSTM cell, f32x2-packed (v_pk_* on gfx950), shared-rcp sigmoids.
// Inputs PRESCALED: i,f,o rows by log2e; g rows by 2*log2e.
// Per unit: R = rcp((1+ei)(1+ef)(1+eg)(1+eo)); 1/(1+ek) = R*prod_{j!=k}(1+ej).
// 7 trans/unit (5 exp2 + 2 rcp) vs naive 10; all mul/add packed across units.
// Overflow check: |g'|<~24 -> e<2^24 -> P<2^96 << f32 max; rcp err ~1e-7 rel.
__device__ __forceinline__ void cell2p_(f32x2 gi, f32x2 gf, f32x2 gg, f32x2 go,
                                        f32x2& c, f32x2& h) {
    f32x2 ei, ef, eg, eo;
    ei[0] = exp2_(-gi[0]); ei[1] = exp2_(-gi[1]);
    ef[0] = exp2_(-gf[0]); ef[1] = exp2_(-gf[1]);
    eg[0] = exp2_(-gg[0]); eg[1] = exp2_(-gg[1]);
    eo[0] = exp2_(-go[0]); eo[1] = exp2_(-go[1]);
    const f32x2 one = {1.0f, 1.0f};
    f32x2 ai = one + ei, af = one + ef, ag = one + eg, ao = one + eo;
    f32x2 pif = ai * af, pgo = ag * ao;
    f32x2 P = pif * pgo;
    f32x2 R; R[0] = rcp_(P[0]); R[1] = rcp_(P[1]);
    f32x2 I = R * (af * pgo);
    f32x2 F = R * (ai * pgo);
    f32x2 Gt = R * (pif * ao);
    f32x2 O = R * (pif * ag);
    f32x2 G = Gt + Gt - one;            // tanh(g) = 2*sigmoid(2g)-1
    c = F * c + I * G;
    f32x2 ct = c * (-2.0f * LOG2E);
    f32x2 et; et[0] = exp2_(ct[0]); et[1] = exp2_(ct[1]);
    f32x2 den = one + et;
    f32x2 Rt; Rt[0] = rcp_(den[0]); Rt[1] = rcp_(den[1]);
    f32x2 T = Rt + Rt - one;
    h = O * T;
}

// Duplicate-column scheme (8 real cols per chain, B cols 8-15 ≡ cols 0-7):
// every lane addresses col c=b&7, so C[:,8+c]==C[:,c]; lane (q,b<8) keeps
// C-regs {0,1} = units 4q,4q+1; lane (q,b>=8) uses its own regs {2,3} =
// units 4q+2,4q+3. 2 units/lane. No cross-lane traffic.
//
// Per-wave LDS (768 B): col c at c*80: bytes [0..31] hi fp16 units 0..15,
// [32..63] lo residual. Lane writes b32 hi at c*80+uu*2, lo at +32
// (uu = 4q + 2*(b>=8)). B-frag read: b128 at c*80+q*16 =
// [hi u0-7 | hi u8-15 | lo u0-7 | lo u8-15]  (K=32 = [h_hi; h_lo],
// HW-verified layout: col=lane&15 (dup via c), k=8q+e).

// ---------------- phase A: layer 0 (input dim 1), both directions ----------------
struct PA {
    const float *x;
    const float *WihF, *WhhF, *bihF, *bhhF;
    const float *WihB, *WhhB, *bihB, *bhhB;
    char* ws;   // [tile8][t][512B]: col c at c*64: [f u0-15 hi | b u0-15 hi] fp16
};

__global__ __launch_bounds__(256) void phaseA_k(PA p) {
    __shared__ uint4 lds4[4 * 48];   // 4 waves x 768 B
    const int tid = threadIdx.x;
    const int lane = tid & 63;
    const int wv   = tid >> 6;
    char* lds = (char*)lds4 + wv * 768;
    const int q = lane >> 4, b = lane & 15, c = b & 7;
    const bool hi8 = b >= 8;
    const int chain = blockIdx.x * 4 + wv;       // 1024 chains = 512 tiles x 2 dirs
    const int tile = chain >> 1, dir = chain & 1;

    const float* Wih = dir ? p.WihB : p.WihF;
    const float* Whh = dir ? p.WhhB : p.WhhF;
    const float* bih = dir ? p.bihB : p.bihF;
    const float* bhh = dir ? p.bhhB : p.bhhF;

    const float SC0 = LOG2E, SC1 = LOG2E, SC2 = 2.0f*LOG2E, SC3 = LOG2E;

    // A = [Whh | Whh] over K=32 (hi;lo halves use same weights); row = b (0-15)
    half8_t whh0 = packA8s(Whh + (     b)*16 + 8*(q&1), SC0);
    half8_t whh1 = packA8s(Whh + (16 + b)*16 + 8*(q&1), SC1);
    half8_t whh2 = packA8s(Whh + (32 + b)*16 + 8*(q&1), SC2);
    half8_t whh3 = packA8s(Whh + (48 + b)*16 + 8*(q&1), SC3);

    f32x4 bias0 = (ld4_(bih +      4*q) + ld4_(bhh +      4*q)) * SC0;
    f32x4 bias1 = (ld4_(bih + 16 + 4*q) + ld4_(bhh + 16 + 4*q)) * SC1;
    f32x4 bias2 = (ld4_(bih + 32 + 4*q) + ld4_(bhh + 32 + 4*q)) * SC2;
    f32x4 bias3 = (ld4_(bih + 48 + 4*q) + ld4_(bhh + 48 + 4*q)) * SC3;

    f32x4 wihx0 = ld4_(Wih +      4*q) * SC0;   // Wih0 is [64 x 1]
    f32x4 wihx1 = ld4_(Wih + 16 + 4*q) * SC1;
    f32x4 wihx2 = ld4_(Wih + 32 + 4*q) * SC2;
    f32x4 wihx3 = ld4_(Wih + 48 + 4*q) * SC3;

    const int uu  = 4*q + (hi8 ? 2 : 0);   // this lane's unit pair
    const int rdo = c*80 + q*16;           // frag read offset
    const int wro = c*80 + uu*2;           // hi write offset (lo at +32)

    { unsigned int* z = (unsigned int*)lds;       // zero bytes [0,640)
      for (int k = lane; k < 160; k += 64) z[k] = 0u; }
    __builtin_amdgcn_wave_barrier();

    f32x2 cc = {0.f, 0.f};

    const char* xbase = (const char*)p.x + (size_t)tile*8*TT*4;   // uniform
    const int   xoff  = c*TT*4;                                   // invariant voffset
    char*       wsbase = p.ws + (size_t)tile*TT*512;              // uniform
    const int   woff  = c*64 + dir*32 + uu*2;

    auto xld = [&](int u)->float {
        int s = mini_(u, TT-1);
        int t = dir ? (TT-1-s) : s;
        return *(const float*)(xbase + (size_t)t*4 + xoff);
    };

    auto step = [&](float xv, int t) {
        FragU hf; hf.u4 = *(const uint4*)(lds + rdo);
        f32x4 a0 = bias0 + wihx0 * xv;
        f32x4 a1 = bias1 + wihx1 * xv;
        f32x4 a2 = bias2 + wihx2 * xv;
        f32x4 a3 = bias3 + wihx3 * xv;
        a0 = MFMA(whh0, hf.h8, a0);
        a1 = MFMA(whh1, hf.h8, a1);
        a2 = MFMA(whh2, hf.h8, a2);
        a3 = MFMA(whh3, hf.h8, a3);
        f32x2 gi, gf, gg, go;
        gi[0] = hi8 ? a0[2] : a0[0]; gi[1] = hi8 ? a0[3] : a0[1];
        gf[0] = hi8 ? a1[2] : a1[0]; gf[1] = hi8 ? a1[3] : a1[1];
        gg[0] = hi8 ? a2[2] : a2[0]; gg[1] = hi8 ? a2[3] : a2[1];
        go[0] = hi8 ? a3[2] : a3[0]; go[1] = hi8 ? a3[3] : a3[1];
        f32x2 hh2;
        cell2p_(gi, gf, gg, go, cc, hh2);
        float m0 = maskhi_(hh2[0]), m1 = maskhi_(hh2[1]);
        unsigned int hh = pkrtz_(m0, m1), hl = pkrtz_(hh2[0] - m0, hh2[1] - m1);
        *(unsigned int*)(lds + wro) = hh;
        *(unsigned int*)(lds + wro + 32) = hl;
        *(unsigned int*)(wsbase + (size_t)t*512 + woff) = hh;
        __builtin_amdgcn_wave_barrier();
    };

    float xv0 = xld(0), xv1 = xld(1), xv2 = xld(2), xv3 = xld(3);
    for (int s = 0; s < TT; s += 4) {
        const int t0 = dir ? (TT-1-s) : s;
        const int d  = dir ? -1 : 1;
        step(xv0, t0      ); xv0 = xld(s+4);
        step(xv1, t0 + d  ); xv1 = xld(s+5);
        step(xv2, t0 + 2*d); xv2 = xld(s+6);
        step(xv3, t0 + 3*d); xv3 = xld(s+7);
    }
}

// ---------------- phase B: layer 1 (input dim 32 from ws), both directions ----------------
struct PB {
    const float *WihF, *WhhF, *bihF, *bhhF;
    const float *WihB, *WhhB, *bihB, *bhhB;
    const char* ws;
    float* hT;   // [dir][tile8][c][16] f32
};

__global__ __launch_bounds__(256) void phaseB_k(PB p) {
    __shared__ uint4 lds4[4 * 48];
    const int tid = threadIdx.x;
    const int lane = tid & 63;
    const int wv   = tid >> 6;
    char* lds = (char*)lds4 + wv * 768;
    const int q = lane >> 4, b = lane & 15, c = b & 7;
    const bool hi8 = b >= 8;
    const int chain = blockIdx.x * 4 + wv;
    const int tile = chain >> 1, dir = chain & 1;

    const float* Wih = dir ? p.WihB : p.WihF;
    const float* Whh = dir ? p.WhhB : p.WhhF;
    const float* bih = dir ? p.bihB : p.bihF;
    const float* bhh = dir ? p.bhhB : p.bhhF;

    const float SC0 = LOG2E, SC1 = LOG2E, SC2 = 2.0f*LOG2E, SC3 = LOG2E;

    half8_t wih0 = packA8s(Wih + (     b)*32 + 8*q, SC0);  // K=32 = [h0f;h0b]
    half8_t wih1 = packA8s(Wih + (16 + b)*32 + 8*q, SC1);
    half8_t wih2 = packA8s(Wih + (32 + b)*32 + 8*q, SC2);
    half8_t wih3 = packA8s(Wih + (48 + b)*32 + 8*q, SC3);

    half8_t whh0 = packA8s(Whh + (     b)*16 + 8*(q&1), SC0);
    half8_t whh1 = packA8s(Whh + (16 + b)*16 + 8*(q&1), SC1);
    half8_t whh2 = packA8s(Whh + (32 + b)*16 + 8*(q&1), SC2);
    half8_t whh3 = packA8s(Whh + (48 + b)*16 + 8*(q&1), SC3);

    f32x4 bias0 = (ld4_(bih +      4*q) + ld4_(bhh +      4*q)) * SC0;
    f32x4 bias1 = (ld4_(bih + 16 + 4*q) + ld4_(bhh + 16 + 4*q)) * SC1;
    f32x4 bias2 = (ld4_(bih + 32 + 4*q) + ld4_(bhh + 32 + 4*q)) * SC2;
    f32x4 bias3 = (ld4_(bih + 48 + 4*q) + ld4_(bhh + 48 + 4*q)) * SC3;

    const int uu  = 4*q + (hi8 ? 2 : 0);
    const int rdo = c*80 + q*16;
    const int wro = c*80 + uu*2;

    { unsigned int* z = (unsigned int*)lds;
      for (int k = lane; k < 160; k += 64) z[k] = 0u; }
    __builtin_amdgcn_wave_barrier();

    f32x2 cc = {0.f, 0.f};
    f32x2 hv = {0.f, 0.f};

    const char* wsbase = p.ws + (size_t)tile*TT*512;   // uniform
    const int   xoff   = c*64 + q*16;                  // invariant voffset

    auto xld = [&](int u)->uint4 {
        int s = mini_(u, TT-1);
        int t = dir ? (TT-1-s) : s;
        return *(const uint4*)(wsbase + (size_t)t*512 + xoff);
    };

    auto step = [&](uint4 xin) {
        FragU xf; xf.u4 = xin;
        FragU hf; hf.u4 = *(const uint4*)(lds + rdo);
        f32x4 a0 = MFMA(wih0, xf.h8, bias0);
        f32x4 a1 = MFMA(wih1, xf.h8, bias1);
        f32x4 a2 = MFMA(wih2, xf.h8, bias2);
        f32x4 a3 = MFMA(wih3, xf.h8, bias3);
        a0 = MFMA(whh0, hf.h8, a0);
        a1 = MFMA(whh1, hf.h8, a1);
        a2 = MFMA(whh2, hf.h8, a2);
        a3 = MFMA(whh3, hf.h8, a3);
        f32x2 gi, gf, gg, go;
        gi[0] = hi8 ? a0[2] : a0[0]; gi[1] = hi8 ? a0[3] : a0[1];
        gf[0] = hi8 ? a1[2] : a1[0]; gf[1] = hi8 ? a1[3] : a1[1];
        gg[0] = hi8 ? a2[2] : a2[0]; gg[1] = hi8 ? a2[3] : a2[1];
        go[0] = hi8 ? a3[2] : a3[0]; go[1] = hi8 ? a3[3] : a3[1];
        cell2p_(gi, gf, gg, go, cc, hv);
        float m0 = maskhi_(hv[0]), m1 = maskhi_(hv[1]);
        unsigned int hh = pkrtz_(m0, m1), hl = pkrtz_(hv[0] - m0, hv[1] - m1);
        *(unsigned int*)(lds + wro) = hh;
        *(unsigned int*)(lds + wro + 32) = hl;
        __builtin_amdgcn_wave_barrier();
    };

    uint4 xb0 = xld(0), xb1 = xld(1), xb2 = xld(2), xb3 = xld(3);
    for (int s = 0; s < TT; s += 4) {
        step(xb0); xb0 = xld(s+4);
        step(xb1); xb1 = xld(s+5);
        step(xb2); xb2 = xld(s+6);
        step(xb3); xb3 = xld(s+7);
    }

    // each lane writes its unit pair (f32x2) — union over lanes = all 16 units x 8 cols
    float* hp = p.hT + ((size_t)(dir*NT8 + tile)*8 + c)*16 + uu;
    float2 ho; ho.x = hv[0]; ho.y = hv[1];
    *(float2*)hp = ho;
}

// ---------------- phase C: MLP head ----------------
struct PC {
    const float* hT;
    const float *W1, *b1, *W2, *b2;
    float* out;
};

__global__ __launch_bounds__(64) void head_k(PC p) {
    const int B = blockIdx.x * 64 + threadIdx.x;
    const int tile = B >> 3, c = B & 7;
    const float* hf = p.hT + ((size_t)(         tile)*8 + c)*16;
    const float* hb = p.hT + ((size_t)(NT8 + tile)*8 + c)*16;

    float z0[32];
#pragma unroll
    for (int k = 0; k < 16; ++k) z0[k] = elu_(hb[k]);       // feat = [hT_b, hT_f]
#pragma unroll
    for (int k = 0; k < 16; ++k) z0[16+k] = elu_(hf[k]);

    float z1[25];
#pragma unroll
    for (int o = 0; o < 25; ++o) {
        float a = p.b1[o];
#pragma unroll
        for (int k = 0; k < 32; ++k) a = fmaf(p.W1[o*32 + k], z0[k], a);
        z1[o] = elu_(a);
    }
#pragma unroll
    for (int o = 0; o < 20; ++o) {
        float a = p.b2[o];
#pragma unroll
        for (int k = 0; k < 25; ++k) a = fmaf(p.W2[o*25 + k], z1[k], a);
        p.out[(size_t)B*20 + o] = elu_(a);
    }
}

extern "C" void kernel_launch(void* const* d_in, const int* in_sizes, int n_in,
                              void* d_out, int out_size, void* d_ws, size_t ws_size,
                              hipStream_t stream) {
    (void)in_sizes; (void)n_in; (void)out_size;

    const size_t frag_bytes = (size_t)NT8 * TT * 512;                   // 128 MiB
    const size_t hT_bytes   = (size_t)2 * NT8 * 8 * 16 * sizeof(float); // 512 KiB
    size_t hT_off = (ws_size >= frag_bytes + hT_bytes) ? frag_bytes
                                                       : (ws_size - hT_bytes);
    char* ws = (char*)d_ws;
    float* hT = (float*)(ws + hT_off);

    PA pa;
    pa.x = (const float*)d_in[0];
    pa.WihF = (const float*)d_in[1];  pa.WhhF = (const float*)d_in[2];
    pa.bihF = (const float*)d_in[3];  pa.bhhF = (const float*)d_in[4];
    pa.WihB = (const float*)d_in[5];  pa.WhhB = (const float*)d_in[6];
    pa.bihB = (const float*)d_in[7];  pa.bhhB = (const float*)d_in[8];
    pa.ws = ws;
    hipLaunchKernelGGL(phaseA_k, dim3(256), dim3(256), 0, stream, pa);

    PB pb;
    pb.WihF = (const float*)d_in[9];   pb.WhhF = (const float*)d_in[10];
    pb.bihF = (const float*)d_in[11];  pb.bhhF = (const float*)d_in[12];
    pb.WihB = (const float*)d_in[13];  pb.WhhB = (const float*)d_in[14];
    pb.bihB = (const float*)d_in[15];  pb.bhhB = (const float*)d_in[16];
    pb.ws = ws; pb.hT = hT;
    hipLaunchKernelGGL(phaseB_k, dim3(256), dim3(256), 0, stream, pb);

    PC pc;
    pc.hT = hT;
    pc.W1 = (const float*)d_in[17]; pc.b1 = (const float*)d_in[18];
    pc.W2 = (const float*)d_in[19]; pc.b2 = (const float*)d_in[20];
    pc.out = (float*)d_out;
    hipLaunchKernelGGL(head_k, dim3(BB/64), dim3(64), 0, stream, pc);
}